// Round 14
// baseline (442.149 us; speedup 1.0000x reference)
//
#include <hip/hip_runtime.h>
#include <hip/hip_bf16.h>

#define HH 64
#define RR 32
#define SILU_SCALE (1.0f / 0.6f)
#define INV_SQRT_3 0.57735026918962576f
#define INV_SQRT_H 0.125f   // 1/sqrt(64)
#define SB 256              // scan block size

typedef __attribute__((ext_vector_type(8))) short short8;
typedef __attribute__((ext_vector_type(4))) float f32x4;

__device__ __forceinline__ int rdlane_i(int v, int l) {
    return __builtin_amdgcn_readlane(v, l);
}
__device__ __forceinline__ float rdlane_f(float v, int l) {
    return __uint_as_float(__builtin_amdgcn_readlane(__float_as_uint(v), l));
}
__device__ __forceinline__ ushort bf16u(float x) {
    __hip_bfloat16 h = __float2bfloat16(x);
    return *(ushort*)&h;
}
__device__ __forceinline__ float bf16f(ushort u) {
    return __uint_as_float((unsigned int)u << 16);
}

// ---------------------------------------------------------------------------
// Kernel 1: feat_w -> packed table pk[n][c] = (bf16(fw)<<16)|bf16(vf).
// Fused target histogram (cnt pre-zeroed by host memset). (Verified r13.)
// ---------------------------------------------------------------------------
__global__ __launch_bounds__(256) void feat2_kernel(
    const float* __restrict__ nf,
    const float* __restrict__ vf,
    const int*   __restrict__ ei,
    const float* __restrict__ Wf1, const float* __restrict__ bf1,
    const float* __restrict__ Wf2, const float* __restrict__ bf2,
    unsigned int* __restrict__ pk, int* __restrict__ cnt, int N, int E)
{
    __shared__ float sW1[64 * 32];
    __shared__ float sW2[32 * 192];
    __shared__ float sb1[32];
    __shared__ float sb2[192];
    __shared__ float snf[8 * 66];   // 64 + 2 pad
    __shared__ float sh[8 * 34];    // 32 + 2 pad

    const int tid = threadIdx.x;
    // histogram (cnt zeroed by memset before this kernel)
    for (int e = blockIdx.x * 256 + tid; e < E; e += gridDim.x * 256)
        atomicAdd(&cnt[ei[E + e]], 1);

    for (int i = tid; i < 64 * 32; i += 256) sW1[i] = Wf1[i];
    for (int i = tid; i < 32 * 192; i += 256) sW2[i] = Wf2[i];
    if (tid < 32) sb1[tid] = bf1[tid];
    if (tid < 192) sb2[tid] = bf2[tid];
    __syncthreads();

    const int sub = tid >> 5;
    const int l32 = tid & 31;

    for (int n0 = blockIdx.x * 8; n0 < N; n0 += gridDim.x * 8) {
        const int nrem = min(8, N - n0);
        for (int i = tid; i < nrem * 64; i += 256)
            snf[(i >> 6) * 66 + (i & 63)] = nf[(size_t)n0 * 64 + i];
        __syncthreads();

        const int n = n0 + sub;
        {
            float a = sb1[l32];
            const float* x = &snf[sub * 66];
            #pragma unroll
            for (int i = 0; i < 64; ++i)
                a = fmaf(x[i], sW1[i * 32 + l32], a);
            sh[sub * 34 + l32] = a / (1.0f + __expf(-a)) * SILU_SCALE;
        }
        // sh written/read within the same 32-lane group -> no barrier
        if (n < N) {
            #pragma unroll
            for (int k = 0; k < 6; ++k) {
                const int col = l32 + 32 * k;
                const float vvf = vf[(size_t)n * 192 + col];
                float o = sb2[col];
                #pragma unroll
                for (int j = 0; j < 32; ++j)
                    o = fmaf(sh[sub * 34 + j], sW2[j * 192 + col], o);
                pk[(size_t)n * 192 + col] =
                    ((unsigned int)bf16u(o) << 16) | (unsigned int)bf16u(vvf);
            }
        }
        __syncthreads();
    }
}

// ---------------------------------------------------------------------------
// Counting sort by target: scan -> fill (int4 meta: 16B/edge random)
// ---------------------------------------------------------------------------
__global__ __launch_bounds__(SB) void scanA_kernel(
    const int* __restrict__ cnt, int* __restrict__ ptr,
    int* __restrict__ bsum, int N)
{
    __shared__ int s[SB];
    const int t = threadIdx.x;
    const int i = blockIdx.x * SB + t;
    const int v = (i < N) ? cnt[i] : 0;
    s[t] = v; __syncthreads();
    for (int off = 1; off < SB; off <<= 1) {
        int x = (t >= off) ? s[t - off] : 0;
        __syncthreads();
        s[t] += x;
        __syncthreads();
    }
    if (i < N) ptr[i] = s[t] - v;
    if (t == SB - 1) bsum[blockIdx.x] = s[t];
}

__global__ __launch_bounds__(SB) void scanB_kernel(
    int* __restrict__ bsum, int nb, int* __restrict__ ptr, int N, int E)
{
    __shared__ int s[SB];
    const int t = threadIdx.x;
    int carry = 0;
    for (int base = 0; base < nb; base += SB) {
        const int i = base + t;
        const int v = (i < nb) ? bsum[i] : 0;
        s[t] = v; __syncthreads();
        for (int off = 1; off < SB; off <<= 1) {
            int x = (t >= off) ? s[t - off] : 0;
            __syncthreads();
            s[t] += x;
            __syncthreads();
        }
        const int total = s[SB - 1];
        if (i < nb) bsum[i] = carry + s[t] - v;
        carry += total;
        __syncthreads();
    }
    if (t == 0) ptr[N] = E;
}

__global__ __launch_bounds__(SB) void scanC_kernel(
    int* __restrict__ ptr, int* __restrict__ head,
    const int* __restrict__ bsum, int N)
{
    const int i = blockIdx.x * SB + threadIdx.x;
    if (i < N) {
        const int p = ptr[i] + bsum[blockIdx.x];
        ptr[i] = p;
        head[i] = p;
    }
}

__global__ __launch_bounds__(256) void fill4_kernel(
    const int* __restrict__ ei, int* __restrict__ head,
    int4* __restrict__ meta, int E)
{
    for (int e = blockIdx.x * blockDim.x + threadIdx.x; e < E;
         e += gridDim.x * blockDim.x) {
        const int t = ei[E + e];
        const int pos = atomicAdd(&head[t], 1);
        meta[pos] = make_int4(e, ei[e], t, 0);
    }
}

// ---------------------------------------------------------------------------
// agg12 = agg11 (r13-verified) with:
//  (1) perfect-balance launch: grid = nchunk/16 blocks -> every wave does
//      exactly 4 chunks (nchunk = 16*grid when E%16==0), no grid-stride tail
//  (2) bias + 1/sqrt3 folded into MFMA (r7-scalar-verified): sBf pre-scaled,
//      C-init = br[col]*IS3 -> math loop drops 3 fadd + 3 fmul per edge-lane
// ---------------------------------------------------------------------------
__global__ __launch_bounds__(256, 4) void agg12_kernel(
    const unsigned int* __restrict__ pk,   // [N,192] packed bf16 (fw|vf)
    const float* __restrict__ rad,         // [E,32] f32, edge order
    const float* __restrict__ ev,          // [E,3]  edge order
    const float* __restrict__ Wr,          // [32,192]
    const float* __restrict__ br,          // [192]
    const int4* __restrict__ meta,         // [E] (edge,src,tgt,0) CSR-sorted
    float* __restrict__ out_s,             // [N,64]
    float* __restrict__ out_v,             // [N,3,64]
    int E)
{
    __shared__ __align__(16) ushort sBf[12 * 64 * 8];    // 12KB Wr B-frags
    __shared__ __align__(16) ushort Pl[4][16 * 200];     // 25.6KB P slices

    const int tid  = threadIdx.x;
    const int lane = tid & 63;
    const int w    = tid >> 6;
    const int mr   = lane & 15;
    const int kk   = (lane >> 4) * 8;       // k offset in bf16 elems

    // stage B fragments, PRE-SCALED by 1/sqrt3 (r7-scalar-verified)
    for (int i = tid; i < 12 * 64 * 8; i += 256) {
        const int nt = i >> 9;
        const int l  = (i >> 3) & 63;
        const int j  = i & 7;
        sBf[i] = bf16u(Wr[(((l >> 4) & 3) * 8 + j) * 192 + nt * 16 + (l & 15)]
                       * INV_SQRT_3);
    }
    __syncthreads();

    // per-lane C-init bias: this lane's column in tile nt is nt*16+mr
    float brc[12];
    #pragma unroll
    for (int nt = 0; nt < 12; ++nt) brc[nt] = br[nt * 16 + mr] * INV_SQRT_3;

    ushort* Pw = Pl[w];
    const int gwave  = blockIdx.x * 4 + w;
    const int nwaves = gridDim.x * 4;
    const int nchunk = (E + 15) >> 4;

    for (int c = gwave; c < nchunk; c += nwaves) {
        const int base = c << 4;
        const int m = min(16, E - base);
        const int idx = min(base + mr, E - 1);
        const int4 mt = meta[idx];           // slot mr's (edge, src, tgt)

        // A fragment source: f32 rad row (r6/r9-verified)
        const float* rp = rad + (size_t)mt.x * RR + kk;
        const float4 ra = *(const float4*)rp;
        const float4 rb = *(const float4*)(rp + 4);

        // ---- wave-parallel ev hoist (r13-verified) ----
        const int sl  = lane / 3;                    // 0..21
        const int sle = min(sl, m - 1);              // clamp (<16)
        const int esl = __shfl(mt.x, sle);           // edge id at that slot
        const float evv = ev[3 * (size_t)esl + (lane - 3 * sl)];

        // ---- hoisted pk gathers: all 16 slots, statically indexed ----
        unsigned int u0[16], u1[16], u2[16];
        #pragma unroll
        for (int i = 0; i < 16; ++i) {
            const int sc = rdlane_i(mt.y, min(i, m - 1));   // SGPR idx
            const unsigned int* pp = pk + (size_t)sc * 192;
            u0[i] = pp[lane];
            u1[i] = pp[64 + lane];
            u2[i] = pp[128 + lane];
        }

        short8 a0;
        a0[0] = (short)bf16u(ra.x); a0[1] = (short)bf16u(ra.y);
        a0[2] = (short)bf16u(ra.z); a0[3] = (short)bf16u(ra.w);
        a0[4] = (short)bf16u(rb.x); a0[5] = (short)bf16u(rb.y);
        a0[6] = (short)bf16u(rb.z); a0[7] = (short)bf16u(rb.w);

        // MFMA with bias C-init: P = (rad@Wr + br)*IS3 -> bf16 LDS (swizzled)
        #pragma unroll
        for (int nt = 0; nt < 12; ++nt) {
            const short8 b = *(const short8*)&sBf[(nt * 64 + lane) * 8];
            f32x4 c0 = {brc[nt], brc[nt], brc[nt], brc[nt]};
            c0 = __builtin_amdgcn_mfma_f32_16x16x32_bf16(a0, b, c0, 0, 0, 0);
            #pragma unroll
            for (int r = 0; r < 4; ++r) {
                const int row = ((lane >> 4) << 2) + r;   // C: row=(lane>>4)*4+reg
                *(ushort*)((char*)Pw + row * 400 +
                           ((nt * 32 + mr * 2) ^ ((row & 12) << 3))) = bf16u(c0[r]);
            }
        }

        // run-boundary flags (r5/r12-verified)
        const int tg = mt.z;
        const int tnext = __shfl(tg, min(mr + 1, 15));
        const int bnd = (mr == m - 1) || (tnext != tg);

        // --- math loop (r13-verified structure; bias/scale pre-folded) ---
        float as = 0.f, ax = 0.f, ay = 0.f, az = 0.f;
        #pragma unroll
        for (int i = 0; i < 16; ++i) {
            if (i >= m) break;               // wave-uniform
            const int t  = rdlane_i(mt.z, i);
            const int fl = rdlane_i(bnd, i);
            const float ex = rdlane_f(evv, 3 * i + 0);
            const float ey = rdlane_f(evv, 3 * i + 1);
            const float ez = rdlane_f(evv, 3 * i + 2);

            const int swz = (i & 12) << 3;
            const char* prow = (const char*)Pw + i * 400;
            ushort q1 = *(const ushort*)(prow + ((lane * 2) ^ swz));
            ushort q2 = *(const ushort*)(prow + (((64 + lane) * 2) ^ swz));
            ushort q3 = *(const ushort*)(prow + (((128 + lane) * 2) ^ swz));
            const float p1 = bf16f(q1);
            const float p2 = bf16f(q2);
            const float p3 = bf16f(q3);

            const float f1 = __uint_as_float(u0[i] & 0xFFFF0000u);
            const float f2 = __uint_as_float(u1[i] & 0xFFFF0000u);
            const float f3 = __uint_as_float(u2[i] & 0xFFFF0000u);
            const float v1 = __uint_as_float(u0[i] << 16);
            const float v2 = __uint_as_float(u1[i] << 16);
            const float v3 = __uint_as_float(u2[i] << 16);

            const float cc1 = f1 * p1;
            const float cc2 = f2 * p2;

            as = fmaf(f3, p3, as);
            ax = fmaf(cc1, v1, fmaf(cc2, ex, ax));
            ay = fmaf(cc1, v2, fmaf(cc2, ey, ay));
            az = fmaf(cc1, v3, fmaf(cc2, ez, az));

            if (fl) {   // wave-uniform flush at target-run boundary
                unsafeAtomicAdd(&out_s[(size_t)t * 64 + lane], as);
                unsafeAtomicAdd(&out_v[(size_t)t * 192 + lane],       ax * INV_SQRT_H);
                unsafeAtomicAdd(&out_v[(size_t)t * 192 + 64 + lane],  ay * INV_SQRT_H);
                unsafeAtomicAdd(&out_v[(size_t)t * 192 + 128 + lane], az * INV_SQRT_H);
                as = ax = ay = az = 0.f;
            }
        }
    }
}

// ---------------------------------------------------------------------------
// Fallback (atomic scatter) if ws can't hold scratch; uses packed table.
// ---------------------------------------------------------------------------
__global__ __launch_bounds__(256) void edge_kernel_atomic(
    const unsigned int* __restrict__ pk, const int* __restrict__ ei,
    const float* __restrict__ rad, const float* __restrict__ ev,
    const float* __restrict__ Wr, const float* __restrict__ br,
    float* __restrict__ out_s, float* __restrict__ out_v, int E)
{
    const int lane = threadIdx.x & 63;
    const int wid  = __builtin_amdgcn_readfirstlane((int)(threadIdx.x >> 6));
    const int wavesPerBlock = blockDim.x >> 6;
    const int totalWaves = gridDim.x * wavesPerBlock;
    const int w0 = blockIdx.x * wavesPerBlock + wid;

    float c1[RR], c2[RR], c3[RR];
    #pragma unroll
    for (int r = 0; r < RR; ++r) {
        c1[r] = Wr[r * 192 + lane];
        c2[r] = Wr[r * 192 + 64 + lane];
        c3[r] = Wr[r * 192 + 128 + lane];
    }
    const float b1 = br[lane], b2 = br[64 + lane], b3 = br[128 + lane];

    for (int e = w0; e < E; e += totalWaves) {
        const int eu  = __builtin_amdgcn_readfirstlane(e);
        const int src = ei[eu];
        const int tgt = ei[E + eu];

        const float* rp = rad + (size_t)eu * RR;
        float w1 = b1, w2 = b2, w3 = b3;
        #pragma unroll
        for (int r = 0; r < RR; ++r) {
            const float rv = rp[r];
            w1 = fmaf(rv, c1[r], w1);
            w2 = fmaf(rv, c2[r], w2);
            w3 = fmaf(rv, c3[r], w3);
        }

        const float evx = ev[eu * 3 + 0];
        const float evy = ev[eu * 3 + 1];
        const float evz = ev[eu * 3 + 2];

        const unsigned int* pp = pk + (size_t)src * 192;
        const unsigned int u1 = pp[lane], u2 = pp[64 + lane], u3 = pp[128 + lane];
        const float f1 = __uint_as_float(u1 & 0xFFFF0000u);
        const float f2 = __uint_as_float(u2 & 0xFFFF0000u);
        const float f3 = __uint_as_float(u3 & 0xFFFF0000u);
        const float v1 = __uint_as_float(u1 << 16);
        const float v2 = __uint_as_float(u2 << 16);
        const float v3 = __uint_as_float(u3 << 16);

        const float cc1 = f1 * w1 * INV_SQRT_3;
        const float cc2 = f2 * w2 * INV_SQRT_3;
        const float cc3 = f3 * w3 * INV_SQRT_3;

        unsafeAtomicAdd(&out_s[(size_t)tgt * 64 + lane], cc3);
        unsafeAtomicAdd(&out_v[(size_t)tgt * 192 + lane],
                        (cc1 * v1 + cc2 * evx) * INV_SQRT_H);
        unsafeAtomicAdd(&out_v[(size_t)tgt * 192 + 64 + lane],
                        (cc1 * v2 + cc2 * evy) * INV_SQRT_H);
        unsafeAtomicAdd(&out_v[(size_t)tgt * 192 + 128 + lane],
                        (cc1 * v3 + cc2 * evz) * INV_SQRT_H);
    }
}

extern "C" void kernel_launch(void* const* d_in, const int* in_sizes, int n_in,
                              void* d_out, int out_size, void* d_ws, size_t ws_size,
                              hipStream_t stream) {
    const float* nf  = (const float*)d_in[0];
    const float* vf  = (const float*)d_in[1];
    const int*   ei  = (const int*)  d_in[2];
    const float* rad = (const float*)d_in[3];
    const float* ev  = (const float*)d_in[4];
    const float* Wf1 = (const float*)d_in[5];
    const float* bf1 = (const float*)d_in[6];
    const float* Wf2 = (const float*)d_in[7];
    const float* bf2 = (const float*)d_in[8];
    const float* Wr  = (const float*)d_in[9];
    const float* br  = (const float*)d_in[10];

    const int N = in_sizes[0] / HH;
    const int E = in_sizes[2] / 2;
    const int nb = (N + SB - 1) / SB;

    float* out_s = (float*)d_out;                // [N,64]
    float* out_v = out_s + (size_t)N * HH;       // [N,3,64]

    // ws layout
    char* ws = (char*)d_ws;
    size_t off = 0;
    unsigned int* pkt = (unsigned int*)(ws + off); off += (size_t)N * 192 * 4;
    int* cnt  = (int*)(ws + off);     off += (size_t)N * 4;
    int* ptr  = (int*)(ws + off);     off += (size_t)(N + 1) * 4;
    int* head = (int*)(ws + off);     off += (size_t)N * 4;
    int* bsum = (int*)(ws + off);     off += (size_t)nb * 4;
    off = (off + 15) & ~(size_t)15;
    int4* meta = (int4*)(ws + off);   off += (size_t)E * 16;

    const int fgrid = min(1280, (N + 7) / 8) > 0 ? min(1280, (N + 7) / 8) : 1;

    if (off <= ws_size) {
        // cnt must be zero before feat2's fused histogram
        hipMemsetAsync(cnt, 0, (size_t)N * 4, stream);
        feat2_kernel<<<fgrid, 256, 0, stream>>>(nf, vf, ei, Wf1, bf1, Wf2, bf2,
                                                pkt, cnt, N, E);
        // outputs accumulated via atomic flushes -> zero first
        hipMemsetAsync(d_out, 0, (size_t)out_size * sizeof(float), stream);

        scanA_kernel<<<nb, SB, 0, stream>>>(cnt, ptr, bsum, N);
        scanB_kernel<<<1, SB, 0, stream>>>(bsum, nb, ptr, N, E);
        scanC_kernel<<<nb, SB, 0, stream>>>(ptr, head, bsum, N);
        fill4_kernel<<<2048, 256, 0, stream>>>(ei, head, meta, E);

        // perfect balance: 4 waves/block x 4 chunks/wave = 16 chunks/block
        const int nchunk = (E + 15) >> 4;
        const int agrid = (nchunk + 15) / 16;
        agg12_kernel<<<agrid, 256, 0, stream>>>(pkt, rad, ev, Wr, br,
                                                meta, out_s, out_v, E);
    } else {
        hipMemsetAsync(cnt, 0, (size_t)N * 4, stream);
        feat2_kernel<<<fgrid, 256, 0, stream>>>(nf, vf, ei, Wf1, bf1, Wf2, bf2,
                                                pkt, cnt, N, E);
        hipMemsetAsync(d_out, 0, (size_t)out_size * sizeof(float), stream);
        edge_kernel_atomic<<<2048, 256, 0, stream>>>(pkt, ei, rad, ev, Wr, br,
                                                     out_s, out_v, E);
    }
}

// Round 15
// 414.022 us; speedup vs baseline: 1.0679x; 1.0679x over previous
//
#include <hip/hip_runtime.h>
#include <hip/hip_bf16.h>

#define HH 64
#define RR 32
#define SILU_SCALE (1.0f / 0.6f)
#define INV_SQRT_3 0.57735026918962576f
#define INV_SQRT_H 0.125f   // 1/sqrt(64)
#define SB 256              // scan block size

typedef __attribute__((ext_vector_type(8))) short short8;
typedef __attribute__((ext_vector_type(4))) float f32x4;

__device__ __forceinline__ int rdlane_i(int v, int l) {
    return __builtin_amdgcn_readlane(v, l);
}
__device__ __forceinline__ float rdlane_f(float v, int l) {
    return __uint_as_float(__builtin_amdgcn_readlane(__float_as_uint(v), l));
}
__device__ __forceinline__ ushort bf16u(float x) {
    __hip_bfloat16 h = __float2bfloat16(x);
    return *(ushort*)&h;
}
__device__ __forceinline__ float bf16f(ushort u) {
    return __uint_as_float((unsigned int)u << 16);
}

// ---------------------------------------------------------------------------
// Kernel 1: feat_w -> packed table pk[n][c] = (bf16(fw)<<16)|bf16(vf).
// Fused target histogram (cnt pre-zeroed by host memset). (Verified r13/r14.)
// ---------------------------------------------------------------------------
__global__ __launch_bounds__(256) void feat2_kernel(
    const float* __restrict__ nf,
    const float* __restrict__ vf,
    const int*   __restrict__ ei,
    const float* __restrict__ Wf1, const float* __restrict__ bf1,
    const float* __restrict__ Wf2, const float* __restrict__ bf2,
    unsigned int* __restrict__ pk, int* __restrict__ cnt, int N, int E)
{
    __shared__ float sW1[64 * 32];
    __shared__ float sW2[32 * 192];
    __shared__ float sb1[32];
    __shared__ float sb2[192];
    __shared__ float snf[8 * 66];   // 64 + 2 pad
    __shared__ float sh[8 * 34];    // 32 + 2 pad

    const int tid = threadIdx.x;
    // histogram (cnt zeroed by memset before this kernel)
    for (int e = blockIdx.x * 256 + tid; e < E; e += gridDim.x * 256)
        atomicAdd(&cnt[ei[E + e]], 1);

    for (int i = tid; i < 64 * 32; i += 256) sW1[i] = Wf1[i];
    for (int i = tid; i < 32 * 192; i += 256) sW2[i] = Wf2[i];
    if (tid < 32) sb1[tid] = bf1[tid];
    if (tid < 192) sb2[tid] = bf2[tid];
    __syncthreads();

    const int sub = tid >> 5;
    const int l32 = tid & 31;

    for (int n0 = blockIdx.x * 8; n0 < N; n0 += gridDim.x * 8) {
        const int nrem = min(8, N - n0);
        for (int i = tid; i < nrem * 64; i += 256)
            snf[(i >> 6) * 66 + (i & 63)] = nf[(size_t)n0 * 64 + i];
        __syncthreads();

        const int n = n0 + sub;
        {
            float a = sb1[l32];
            const float* x = &snf[sub * 66];
            #pragma unroll
            for (int i = 0; i < 64; ++i)
                a = fmaf(x[i], sW1[i * 32 + l32], a);
            sh[sub * 34 + l32] = a / (1.0f + __expf(-a)) * SILU_SCALE;
        }
        // sh written/read within the same 32-lane group -> no barrier
        if (n < N) {
            #pragma unroll
            for (int k = 0; k < 6; ++k) {
                const int col = l32 + 32 * k;
                const float vvf = vf[(size_t)n * 192 + col];
                float o = sb2[col];
                #pragma unroll
                for (int j = 0; j < 32; ++j)
                    o = fmaf(sh[sub * 34 + j], sW2[j * 192 + col], o);
                pk[(size_t)n * 192 + col] =
                    ((unsigned int)bf16u(o) << 16) | (unsigned int)bf16u(vvf);
            }
        }
        __syncthreads();
    }
}

// ---------------------------------------------------------------------------
// Counting sort by target: scan -> fill (int4 meta: 16B/edge random)
// ---------------------------------------------------------------------------
__global__ __launch_bounds__(SB) void scanA_kernel(
    const int* __restrict__ cnt, int* __restrict__ ptr,
    int* __restrict__ bsum, int N)
{
    __shared__ int s[SB];
    const int t = threadIdx.x;
    const int i = blockIdx.x * SB + t;
    const int v = (i < N) ? cnt[i] : 0;
    s[t] = v; __syncthreads();
    for (int off = 1; off < SB; off <<= 1) {
        int x = (t >= off) ? s[t - off] : 0;
        __syncthreads();
        s[t] += x;
        __syncthreads();
    }
    if (i < N) ptr[i] = s[t] - v;
    if (t == SB - 1) bsum[blockIdx.x] = s[t];
}

__global__ __launch_bounds__(SB) void scanB_kernel(
    int* __restrict__ bsum, int nb, int* __restrict__ ptr, int N, int E)
{
    __shared__ int s[SB];
    const int t = threadIdx.x;
    int carry = 0;
    for (int base = 0; base < nb; base += SB) {
        const int i = base + t;
        const int v = (i < nb) ? bsum[i] : 0;
        s[t] = v; __syncthreads();
        for (int off = 1; off < SB; off <<= 1) {
            int x = (t >= off) ? s[t - off] : 0;
            __syncthreads();
            s[t] += x;
            __syncthreads();
        }
        const int total = s[SB - 1];
        if (i < nb) bsum[i] = carry + s[t] - v;
        carry += total;
        __syncthreads();
    }
    if (t == 0) ptr[N] = E;
}

__global__ __launch_bounds__(SB) void scanC_kernel(
    int* __restrict__ ptr, int* __restrict__ head,
    const int* __restrict__ bsum, int N)
{
    const int i = blockIdx.x * SB + threadIdx.x;
    if (i < N) {
        const int p = ptr[i] + bsum[blockIdx.x];
        ptr[i] = p;
        head[i] = p;
    }
}

__global__ __launch_bounds__(256) void fill4_kernel(
    const int* __restrict__ ei, int* __restrict__ head,
    int4* __restrict__ meta, int E)
{
    for (int e = blockIdx.x * blockDim.x + threadIdx.x; e < E;
         e += gridDim.x * blockDim.x) {
        const int t = ei[E + e];
        const int pos = atomicAdd(&head[t], 1);
        meta[pos] = make_int4(e, ei[e], t, 0);
    }
}

// ---------------------------------------------------------------------------
// agg13 = r13's agg11 (verified, 160us @ 2048 blocks) + bias/scale folded
// into the MFMA (r7-scalar-verified; r14-verified-correct). The r14 grid
// change (3125 blocks) is REVERTED: it blew up HBM traffic 525->980MB
// (cache-temporal regression), not a balance win.
// ---------------------------------------------------------------------------
__global__ __launch_bounds__(256, 4) void agg13_kernel(
    const unsigned int* __restrict__ pk,   // [N,192] packed bf16 (fw|vf)
    const float* __restrict__ rad,         // [E,32] f32, edge order
    const float* __restrict__ ev,          // [E,3]  edge order
    const float* __restrict__ Wr,          // [32,192]
    const float* __restrict__ br,          // [192]
    const int4* __restrict__ meta,         // [E] (edge,src,tgt,0) CSR-sorted
    float* __restrict__ out_s,             // [N,64]
    float* __restrict__ out_v,             // [N,3,64]
    int E)
{
    __shared__ __align__(16) ushort sBf[12 * 64 * 8];    // 12KB Wr B-frags
    __shared__ __align__(16) ushort Pl[4][16 * 200];     // 25.6KB P slices

    const int tid  = threadIdx.x;
    const int lane = tid & 63;
    const int w    = tid >> 6;
    const int mr   = lane & 15;
    const int kk   = (lane >> 4) * 8;       // k offset in bf16 elems

    // stage B fragments, PRE-SCALED by 1/sqrt3 (r7/r14-verified)
    for (int i = tid; i < 12 * 64 * 8; i += 256) {
        const int nt = i >> 9;
        const int l  = (i >> 3) & 63;
        const int j  = i & 7;
        sBf[i] = bf16u(Wr[(((l >> 4) & 3) * 8 + j) * 192 + nt * 16 + (l & 15)]
                       * INV_SQRT_3);
    }
    __syncthreads();

    // per-lane C-init bias: this lane's column in tile nt is nt*16+mr
    float brc[12];
    #pragma unroll
    for (int nt = 0; nt < 12; ++nt) brc[nt] = br[nt * 16 + mr] * INV_SQRT_3;

    ushort* Pw = Pl[w];
    const int gwave  = blockIdx.x * 4 + w;
    const int nwaves = gridDim.x * 4;
    const int nchunk = (E + 15) >> 4;

    for (int c = gwave; c < nchunk; c += nwaves) {
        const int base = c << 4;
        const int m = min(16, E - base);
        const int idx = min(base + mr, E - 1);
        const int4 mt = meta[idx];           // slot mr's (edge, src, tgt)

        // A fragment source: f32 rad row (r6/r9-verified)
        const float* rp = rad + (size_t)mt.x * RR + kk;
        const float4 ra = *(const float4*)rp;
        const float4 rb = *(const float4*)(rp + 4);

        // ---- wave-parallel ev hoist (r13-verified) ----
        const int sl  = lane / 3;                    // 0..21
        const int sle = min(sl, m - 1);              // clamp (<16)
        const int esl = __shfl(mt.x, sle);           // edge id at that slot
        const float evv = ev[3 * (size_t)esl + (lane - 3 * sl)];

        // ---- hoisted pk gathers: all 16 slots, statically indexed ----
        unsigned int u0[16], u1[16], u2[16];
        #pragma unroll
        for (int i = 0; i < 16; ++i) {
            const int sc = rdlane_i(mt.y, min(i, m - 1));   // SGPR idx
            const unsigned int* pp = pk + (size_t)sc * 192;
            u0[i] = pp[lane];
            u1[i] = pp[64 + lane];
            u2[i] = pp[128 + lane];
        }

        short8 a0;
        a0[0] = (short)bf16u(ra.x); a0[1] = (short)bf16u(ra.y);
        a0[2] = (short)bf16u(ra.z); a0[3] = (short)bf16u(ra.w);
        a0[4] = (short)bf16u(rb.x); a0[5] = (short)bf16u(rb.y);
        a0[6] = (short)bf16u(rb.z); a0[7] = (short)bf16u(rb.w);

        // MFMA with bias C-init: P = (rad@Wr + br)*IS3 -> bf16 LDS (swizzled)
        #pragma unroll
        for (int nt = 0; nt < 12; ++nt) {
            const short8 b = *(const short8*)&sBf[(nt * 64 + lane) * 8];
            f32x4 c0 = {brc[nt], brc[nt], brc[nt], brc[nt]};
            c0 = __builtin_amdgcn_mfma_f32_16x16x32_bf16(a0, b, c0, 0, 0, 0);
            #pragma unroll
            for (int r = 0; r < 4; ++r) {
                const int row = ((lane >> 4) << 2) + r;   // C: row=(lane>>4)*4+reg
                *(ushort*)((char*)Pw + row * 400 +
                           ((nt * 32 + mr * 2) ^ ((row & 12) << 3))) = bf16u(c0[r]);
            }
        }

        // run-boundary flags (r5/r12-verified)
        const int tg = mt.z;
        const int tnext = __shfl(tg, min(mr + 1, 15));
        const int bnd = (mr == m - 1) || (tnext != tg);

        // --- math loop (r13-verified structure; bias/scale pre-folded) ---
        float as = 0.f, ax = 0.f, ay = 0.f, az = 0.f;
        #pragma unroll
        for (int i = 0; i < 16; ++i) {
            if (i >= m) break;               // wave-uniform
            const int t  = rdlane_i(mt.z, i);
            const int fl = rdlane_i(bnd, i);
            const float ex = rdlane_f(evv, 3 * i + 0);
            const float ey = rdlane_f(evv, 3 * i + 1);
            const float ez = rdlane_f(evv, 3 * i + 2);

            const int swz = (i & 12) << 3;
            const char* prow = (const char*)Pw + i * 400;
            ushort q1 = *(const ushort*)(prow + ((lane * 2) ^ swz));
            ushort q2 = *(const ushort*)(prow + (((64 + lane) * 2) ^ swz));
            ushort q3 = *(const ushort*)(prow + (((128 + lane) * 2) ^ swz));
            const float p1 = bf16f(q1);
            const float p2 = bf16f(q2);
            const float p3 = bf16f(q3);

            const float f1 = __uint_as_float(u0[i] & 0xFFFF0000u);
            const float f2 = __uint_as_float(u1[i] & 0xFFFF0000u);
            const float f3 = __uint_as_float(u2[i] & 0xFFFF0000u);
            const float v1 = __uint_as_float(u0[i] << 16);
            const float v2 = __uint_as_float(u1[i] << 16);
            const float v3 = __uint_as_float(u2[i] << 16);

            const float cc1 = f1 * p1;
            const float cc2 = f2 * p2;

            as = fmaf(f3, p3, as);
            ax = fmaf(cc1, v1, fmaf(cc2, ex, ax));
            ay = fmaf(cc1, v2, fmaf(cc2, ey, ay));
            az = fmaf(cc1, v3, fmaf(cc2, ez, az));

            if (fl) {   // wave-uniform flush at target-run boundary
                unsafeAtomicAdd(&out_s[(size_t)t * 64 + lane], as);
                unsafeAtomicAdd(&out_v[(size_t)t * 192 + lane],       ax * INV_SQRT_H);
                unsafeAtomicAdd(&out_v[(size_t)t * 192 + 64 + lane],  ay * INV_SQRT_H);
                unsafeAtomicAdd(&out_v[(size_t)t * 192 + 128 + lane], az * INV_SQRT_H);
                as = ax = ay = az = 0.f;
            }
        }
    }
}

// ---------------------------------------------------------------------------
// Fallback (atomic scatter) if ws can't hold scratch; uses packed table.
// ---------------------------------------------------------------------------
__global__ __launch_bounds__(256) void edge_kernel_atomic(
    const unsigned int* __restrict__ pk, const int* __restrict__ ei,
    const float* __restrict__ rad, const float* __restrict__ ev,
    const float* __restrict__ Wr, const float* __restrict__ br,
    float* __restrict__ out_s, float* __restrict__ out_v, int E)
{
    const int lane = threadIdx.x & 63;
    const int wid  = __builtin_amdgcn_readfirstlane((int)(threadIdx.x >> 6));
    const int wavesPerBlock = blockDim.x >> 6;
    const int totalWaves = gridDim.x * wavesPerBlock;
    const int w0 = blockIdx.x * wavesPerBlock + wid;

    float c1[RR], c2[RR], c3[RR];
    #pragma unroll
    for (int r = 0; r < RR; ++r) {
        c1[r] = Wr[r * 192 + lane];
        c2[r] = Wr[r * 192 + 64 + lane];
        c3[r] = Wr[r * 192 + 128 + lane];
    }
    const float b1 = br[lane], b2 = br[64 + lane], b3 = br[128 + lane];

    for (int e = w0; e < E; e += totalWaves) {
        const int eu  = __builtin_amdgcn_readfirstlane(e);
        const int src = ei[eu];
        const int tgt = ei[E + eu];

        const float* rp = rad + (size_t)eu * RR;
        float w1 = b1, w2 = b2, w3 = b3;
        #pragma unroll
        for (int r = 0; r < RR; ++r) {
            const float rv = rp[r];
            w1 = fmaf(rv, c1[r], w1);
            w2 = fmaf(rv, c2[r], w2);
            w3 = fmaf(rv, c3[r], w3);
        }

        const float evx = ev[eu * 3 + 0];
        const float evy = ev[eu * 3 + 1];
        const float evz = ev[eu * 3 + 2];

        const unsigned int* pp = pk + (size_t)src * 192;
        const unsigned int u1 = pp[lane], u2 = pp[64 + lane], u3 = pp[128 + lane];
        const float f1 = __uint_as_float(u1 & 0xFFFF0000u);
        const float f2 = __uint_as_float(u2 & 0xFFFF0000u);
        const float f3 = __uint_as_float(u3 & 0xFFFF0000u);
        const float v1 = __uint_as_float(u1 << 16);
        const float v2 = __uint_as_float(u2 << 16);
        const float v3 = __uint_as_float(u3 << 16);

        const float cc1 = f1 * w1 * INV_SQRT_3;
        const float cc2 = f2 * w2 * INV_SQRT_3;
        const float cc3 = f3 * w3 * INV_SQRT_3;

        unsafeAtomicAdd(&out_s[(size_t)tgt * 64 + lane], cc3);
        unsafeAtomicAdd(&out_v[(size_t)tgt * 192 + lane],
                        (cc1 * v1 + cc2 * evx) * INV_SQRT_H);
        unsafeAtomicAdd(&out_v[(size_t)tgt * 192 + 64 + lane],
                        (cc1 * v2 + cc2 * evy) * INV_SQRT_H);
        unsafeAtomicAdd(&out_v[(size_t)tgt * 192 + 128 + lane],
                        (cc1 * v3 + cc2 * evz) * INV_SQRT_H);
    }
}

extern "C" void kernel_launch(void* const* d_in, const int* in_sizes, int n_in,
                              void* d_out, int out_size, void* d_ws, size_t ws_size,
                              hipStream_t stream) {
    const float* nf  = (const float*)d_in[0];
    const float* vf  = (const float*)d_in[1];
    const int*   ei  = (const int*)  d_in[2];
    const float* rad = (const float*)d_in[3];
    const float* ev  = (const float*)d_in[4];
    const float* Wf1 = (const float*)d_in[5];
    const float* bf1 = (const float*)d_in[6];
    const float* Wf2 = (const float*)d_in[7];
    const float* bf2 = (const float*)d_in[8];
    const float* Wr  = (const float*)d_in[9];
    const float* br  = (const float*)d_in[10];

    const int N = in_sizes[0] / HH;
    const int E = in_sizes[2] / 2;
    const int nb = (N + SB - 1) / SB;

    float* out_s = (float*)d_out;                // [N,64]
    float* out_v = out_s + (size_t)N * HH;       // [N,3,64]

    // ws layout
    char* ws = (char*)d_ws;
    size_t off = 0;
    unsigned int* pkt = (unsigned int*)(ws + off); off += (size_t)N * 192 * 4;
    int* cnt  = (int*)(ws + off);     off += (size_t)N * 4;
    int* ptr  = (int*)(ws + off);     off += (size_t)(N + 1) * 4;
    int* head = (int*)(ws + off);     off += (size_t)N * 4;
    int* bsum = (int*)(ws + off);     off += (size_t)nb * 4;
    off = (off + 15) & ~(size_t)15;
    int4* meta = (int4*)(ws + off);   off += (size_t)E * 16;

    const int fgrid = min(1280, (N + 7) / 8) > 0 ? min(1280, (N + 7) / 8) : 1;

    if (off <= ws_size) {
        // cnt must be zero before feat2's fused histogram
        hipMemsetAsync(cnt, 0, (size_t)N * 4, stream);
        feat2_kernel<<<fgrid, 256, 0, stream>>>(nf, vf, ei, Wf1, bf1, Wf2, bf2,
                                                pkt, cnt, N, E);
        // outputs accumulated via atomic flushes -> zero first
        hipMemsetAsync(d_out, 0, (size_t)out_size * sizeof(float), stream);

        scanA_kernel<<<nb, SB, 0, stream>>>(cnt, ptr, bsum, N);
        scanB_kernel<<<1, SB, 0, stream>>>(bsum, nb, ptr, N, E);
        scanC_kernel<<<nb, SB, 0, stream>>>(ptr, head, bsum, N);
        fill4_kernel<<<2048, 256, 0, stream>>>(ei, head, meta, E);

        // 2048 blocks (r13-verified cache-friendly launch shape)
        agg13_kernel<<<2048, 256, 0, stream>>>(pkt, rad, ev, Wr, br,
                                               meta, out_s, out_v, E);
    } else {
        hipMemsetAsync(cnt, 0, (size_t)N * 4, stream);
        feat2_kernel<<<fgrid, 256, 0, stream>>>(nf, vf, ei, Wf1, bf1, Wf2, bf2,
                                                pkt, cnt, N, E);
        hipMemsetAsync(d_out, 0, (size_t)out_size * sizeof(float), stream);
        edge_kernel_atomic<<<2048, 256, 0, stream>>>(pkt, ei, rad, ev, Wr, br,
                                                     out_s, out_v, E);
    }
}

// Round 16
// 320.311 us; speedup vs baseline: 1.3804x; 1.2926x over previous
//
#include <hip/hip_runtime.h>
#include <hip/hip_bf16.h>

#define HH 64
#define RR 32
#define SILU_SCALE (1.0f / 0.6f)
#define INV_SQRT_3 0.57735026918962576f
#define INV_SQRT_H 0.125f   // 1/sqrt(64)
#define SB 256              // scan block size

typedef __attribute__((ext_vector_type(8))) short short8;
typedef __attribute__((ext_vector_type(4))) float f32x4;

__device__ __forceinline__ int rdlane_i(int v, int l) {
    return __builtin_amdgcn_readlane(v, l);
}
__device__ __forceinline__ float rdlane_f(float v, int l) {
    return __uint_as_float(__builtin_amdgcn_readlane(__float_as_uint(v), l));
}
__device__ __forceinline__ ushort bf16u(float x) {
    __hip_bfloat16 h = __float2bfloat16(x);
    return *(ushort*)&h;
}
__device__ __forceinline__ float bf16f(ushort u) {
    return __uint_as_float((unsigned int)u << 16);
}

// ---------------------------------------------------------------------------
// Kernel 1: feat_w -> packed table pk[n][c] = (bf16(fw)<<16)|bf16(vf).
// Fused target histogram (cnt pre-zeroed by host memset). (Verified r13.)
// ---------------------------------------------------------------------------
__global__ __launch_bounds__(256) void feat2_kernel(
    const float* __restrict__ nf,
    const float* __restrict__ vf,
    const int*   __restrict__ ei,
    const float* __restrict__ Wf1, const float* __restrict__ bf1,
    const float* __restrict__ Wf2, const float* __restrict__ bf2,
    unsigned int* __restrict__ pk, int* __restrict__ cnt, int N, int E)
{
    __shared__ float sW1[64 * 32];
    __shared__ float sW2[32 * 192];
    __shared__ float sb1[32];
    __shared__ float sb2[192];
    __shared__ float snf[8 * 66];   // 64 + 2 pad
    __shared__ float sh[8 * 34];    // 32 + 2 pad

    const int tid = threadIdx.x;
    // histogram (cnt zeroed by memset before this kernel)
    for (int e = blockIdx.x * 256 + tid; e < E; e += gridDim.x * 256)
        atomicAdd(&cnt[ei[E + e]], 1);

    for (int i = tid; i < 64 * 32; i += 256) sW1[i] = Wf1[i];
    for (int i = tid; i < 32 * 192; i += 256) sW2[i] = Wf2[i];
    if (tid < 32) sb1[tid] = bf1[tid];
    if (tid < 192) sb2[tid] = bf2[tid];
    __syncthreads();

    const int sub = tid >> 5;
    const int l32 = tid & 31;

    for (int n0 = blockIdx.x * 8; n0 < N; n0 += gridDim.x * 8) {
        const int nrem = min(8, N - n0);
        for (int i = tid; i < nrem * 64; i += 256)
            snf[(i >> 6) * 66 + (i & 63)] = nf[(size_t)n0 * 64 + i];
        __syncthreads();

        const int n = n0 + sub;
        {
            float a = sb1[l32];
            const float* x = &snf[sub * 66];
            #pragma unroll
            for (int i = 0; i < 64; ++i)
                a = fmaf(x[i], sW1[i * 32 + l32], a);
            sh[sub * 34 + l32] = a / (1.0f + __expf(-a)) * SILU_SCALE;
        }
        // sh written/read within the same 32-lane group -> no barrier
        if (n < N) {
            #pragma unroll
            for (int k = 0; k < 6; ++k) {
                const int col = l32 + 32 * k;
                const float vvf = vf[(size_t)n * 192 + col];
                float o = sb2[col];
                #pragma unroll
                for (int j = 0; j < 32; ++j)
                    o = fmaf(sh[sub * 34 + j], sW2[j * 192 + col], o);
                pk[(size_t)n * 192 + col] =
                    ((unsigned int)bf16u(o) << 16) | (unsigned int)bf16u(vvf);
            }
        }
        __syncthreads();
    }
}

// ---------------------------------------------------------------------------
// Counting sort by target: scan -> fill (int4 meta: 16B/edge random)
// ---------------------------------------------------------------------------
__global__ __launch_bounds__(SB) void scanA_kernel(
    const int* __restrict__ cnt, int* __restrict__ ptr,
    int* __restrict__ bsum, int N)
{
    __shared__ int s[SB];
    const int t = threadIdx.x;
    const int i = blockIdx.x * SB + t;
    const int v = (i < N) ? cnt[i] : 0;
    s[t] = v; __syncthreads();
    for (int off = 1; off < SB; off <<= 1) {
        int x = (t >= off) ? s[t - off] : 0;
        __syncthreads();
        s[t] += x;
        __syncthreads();
    }
    if (i < N) ptr[i] = s[t] - v;
    if (t == SB - 1) bsum[blockIdx.x] = s[t];
}

__global__ __launch_bounds__(SB) void scanB_kernel(
    int* __restrict__ bsum, int nb, int* __restrict__ ptr, int N, int E)
{
    __shared__ int s[SB];
    const int t = threadIdx.x;
    int carry = 0;
    for (int base = 0; base < nb; base += SB) {
        const int i = base + t;
        const int v = (i < nb) ? bsum[i] : 0;
        s[t] = v; __syncthreads();
        for (int off = 1; off < SB; off <<= 1) {
            int x = (t >= off) ? s[t - off] : 0;
            __syncthreads();
            s[t] += x;
            __syncthreads();
        }
        const int total = s[SB - 1];
        if (i < nb) bsum[i] = carry + s[t] - v;
        carry += total;
        __syncthreads();
    }
    if (t == 0) ptr[N] = E;
}

__global__ __launch_bounds__(SB) void scanC_kernel(
    int* __restrict__ ptr, int* __restrict__ head,
    const int* __restrict__ bsum, int N)
{
    const int i = blockIdx.x * SB + threadIdx.x;
    if (i < N) {
        const int p = ptr[i] + bsum[blockIdx.x];
        ptr[i] = p;
        head[i] = p;
    }
}

__global__ __launch_bounds__(256) void fill4_kernel(
    const int* __restrict__ ei, int* __restrict__ head,
    int4* __restrict__ meta, int E)
{
    for (int e = blockIdx.x * blockDim.x + threadIdx.x; e < E;
         e += gridDim.x * blockDim.x) {
        const int t = ei[E + e];
        const int pos = atomicAdd(&head[t], 1);
        meta[pos] = make_int4(e, ei[e], t, 0);
    }
}

// ---------------------------------------------------------------------------
// agg11 (r13-verified, 160us): edge-chunk-per-wave + u-hoist + ev-hoist +
// sBf staging (unscaled) + bias in math loop + run-boundary atomic flushes.
// RESTORED BYTE-EXACT after r14/r15 showed the bias-fold perturbation
// triggers a codegen/traffic cliff (+300MB HBM at identical addresses).
// ---------------------------------------------------------------------------
__global__ __launch_bounds__(256, 4) void agg11_kernel(
    const unsigned int* __restrict__ pk,   // [N,192] packed bf16 (fw|vf)
    const float* __restrict__ rad,         // [E,32] f32, edge order
    const float* __restrict__ ev,          // [E,3]  edge order
    const float* __restrict__ Wr,          // [32,192]
    const float* __restrict__ br,          // [192]
    const int4* __restrict__ meta,         // [E] (edge,src,tgt,0) CSR-sorted
    float* __restrict__ out_s,             // [N,64]
    float* __restrict__ out_v,             // [N,3,64]
    int E)
{
    __shared__ __align__(16) ushort sBf[12 * 64 * 8];    // 12KB Wr B-frags
    __shared__ __align__(16) ushort Pl[4][16 * 200];     // 25.6KB P slices

    const int tid  = threadIdx.x;
    const int lane = tid & 63;
    const int w    = tid >> 6;
    const int mr   = lane & 15;
    const int kk   = (lane >> 4) * 8;       // k offset in bf16 elems

    // stage B fragments (r11/r12-verified layout, unscaled)
    for (int i = tid; i < 12 * 64 * 8; i += 256) {
        const int nt = i >> 9;
        const int l  = (i >> 3) & 63;
        const int j  = i & 7;
        sBf[i] = bf16u(Wr[(((l >> 4) & 3) * 8 + j) * 192 + nt * 16 + (l & 15)]);
    }
    __syncthreads();

    const float b1 = br[lane], b2 = br[64 + lane], b3 = br[128 + lane];
    ushort* Pw = Pl[w];
    const int gwave  = blockIdx.x * 4 + w;
    const int nwaves = gridDim.x * 4;
    const int nchunk = (E + 15) >> 4;

    for (int c = gwave; c < nchunk; c += nwaves) {
        const int base = c << 4;
        const int m = min(16, E - base);
        const int idx = min(base + mr, E - 1);
        const int4 mt = meta[idx];           // slot mr's (edge, src, tgt)

        // A fragment source: f32 rad row (r6/r9-verified)
        const float* rp = rad + (size_t)mt.x * RR + kk;
        const float4 ra = *(const float4*)rp;
        const float4 rb = *(const float4*)(rp + 4);

        // ---- wave-parallel ev hoist: lane l holds comp l%3 of slot l/3 ----
        const int sl  = lane / 3;                    // 0..21
        const int sle = min(sl, m - 1);              // clamp (<16)
        const int esl = __shfl(mt.x, sle);           // edge id at that slot
        const float evv = ev[3 * (size_t)esl + (lane - 3 * sl)];

        // ---- hoisted pk gathers: all 16 slots, statically indexed (r11) ----
        unsigned int u0[16], u1[16], u2[16];
        #pragma unroll
        for (int i = 0; i < 16; ++i) {
            const int sc = rdlane_i(mt.y, min(i, m - 1));   // SGPR idx
            const unsigned int* pp = pk + (size_t)sc * 192;
            u0[i] = pp[lane];
            u1[i] = pp[64 + lane];
            u2[i] = pp[128 + lane];
        }

        short8 a0;
        a0[0] = (short)bf16u(ra.x); a0[1] = (short)bf16u(ra.y);
        a0[2] = (short)bf16u(ra.z); a0[3] = (short)bf16u(ra.w);
        a0[4] = (short)bf16u(rb.x); a0[5] = (short)bf16u(rb.y);
        a0[6] = (short)bf16u(rb.z); a0[7] = (short)bf16u(rb.w);

        // MFMA: P[16][192] = A[16][32] @ Wr[32][192] -> bf16 LDS (swizzled)
        #pragma unroll
        for (int nt = 0; nt < 12; ++nt) {
            const short8 b = *(const short8*)&sBf[(nt * 64 + lane) * 8];
            f32x4 c0 = {0.f, 0.f, 0.f, 0.f};
            c0 = __builtin_amdgcn_mfma_f32_16x16x32_bf16(a0, b, c0, 0, 0, 0);
            #pragma unroll
            for (int r = 0; r < 4; ++r) {
                const int row = ((lane >> 4) << 2) + r;   // C: row=(lane>>4)*4+reg
                *(ushort*)((char*)Pw + row * 400 +
                           ((nt * 32 + mr * 2) ^ ((row & 12) << 3))) = bf16u(c0[r]);
            }
        }

        // run-boundary flags (r5/r12-verified)
        const int tg = mt.z;
        const int tnext = __shfl(tg, min(mr + 1, 15));
        const int bnd = (mr == m - 1) || (tnext != tg);

        // --- math loop: r12-verified unrolled sweep; ev via readlane ---
        float as = 0.f, ax = 0.f, ay = 0.f, az = 0.f;
        #pragma unroll
        for (int i = 0; i < 16; ++i) {
            if (i >= m) break;               // wave-uniform
            const int t  = rdlane_i(mt.z, i);
            const int fl = rdlane_i(bnd, i);
            const float ex = rdlane_f(evv, 3 * i + 0);
            const float ey = rdlane_f(evv, 3 * i + 1);
            const float ez = rdlane_f(evv, 3 * i + 2);

            const int swz = (i & 12) << 3;
            const char* prow = (const char*)Pw + i * 400;
            ushort q1 = *(const ushort*)(prow + ((lane * 2) ^ swz));
            ushort q2 = *(const ushort*)(prow + (((64 + lane) * 2) ^ swz));
            ushort q3 = *(const ushort*)(prow + (((128 + lane) * 2) ^ swz));
            const float p1 = bf16f(q1) + b1;
            const float p2 = bf16f(q2) + b2;
            const float p3 = bf16f(q3) + b3;

            const float f1 = __uint_as_float(u0[i] & 0xFFFF0000u);
            const float f2 = __uint_as_float(u1[i] & 0xFFFF0000u);
            const float f3 = __uint_as_float(u2[i] & 0xFFFF0000u);
            const float v1 = __uint_as_float(u0[i] << 16);
            const float v2 = __uint_as_float(u1[i] << 16);
            const float v3 = __uint_as_float(u2[i] << 16);

            const float cc1 = f1 * p1 * INV_SQRT_3;
            const float cc2 = f2 * p2 * INV_SQRT_3;
            const float cc3 = f3 * p3 * INV_SQRT_3;

            as += cc3;
            ax = fmaf(cc1, v1, fmaf(cc2, ex, ax));
            ay = fmaf(cc1, v2, fmaf(cc2, ey, ay));
            az = fmaf(cc1, v3, fmaf(cc2, ez, az));

            if (fl) {   // wave-uniform flush at target-run boundary
                unsafeAtomicAdd(&out_s[(size_t)t * 64 + lane], as);
                unsafeAtomicAdd(&out_v[(size_t)t * 192 + lane],       ax * INV_SQRT_H);
                unsafeAtomicAdd(&out_v[(size_t)t * 192 + 64 + lane],  ay * INV_SQRT_H);
                unsafeAtomicAdd(&out_v[(size_t)t * 192 + 128 + lane], az * INV_SQRT_H);
                as = ax = ay = az = 0.f;
            }
        }
    }
}

// ---------------------------------------------------------------------------
// Fallback (atomic scatter) if ws can't hold scratch; uses packed table.
// ---------------------------------------------------------------------------
__global__ __launch_bounds__(256) void edge_kernel_atomic(
    const unsigned int* __restrict__ pk, const int* __restrict__ ei,
    const float* __restrict__ rad, const float* __restrict__ ev,
    const float* __restrict__ Wr, const float* __restrict__ br,
    float* __restrict__ out_s, float* __restrict__ out_v, int E)
{
    const int lane = threadIdx.x & 63;
    const int wid  = __builtin_amdgcn_readfirstlane((int)(threadIdx.x >> 6));
    const int wavesPerBlock = blockDim.x >> 6;
    const int totalWaves = gridDim.x * wavesPerBlock;
    const int w0 = blockIdx.x * wavesPerBlock + wid;

    float c1[RR], c2[RR], c3[RR];
    #pragma unroll
    for (int r = 0; r < RR; ++r) {
        c1[r] = Wr[r * 192 + lane];
        c2[r] = Wr[r * 192 + 64 + lane];
        c3[r] = Wr[r * 192 + 128 + lane];
    }
    const float b1 = br[lane], b2 = br[64 + lane], b3 = br[128 + lane];

    for (int e = w0; e < E; e += totalWaves) {
        const int eu  = __builtin_amdgcn_readfirstlane(e);
        const int src = ei[eu];
        const int tgt = ei[E + eu];

        const float* rp = rad + (size_t)eu * RR;
        float w1 = b1, w2 = b2, w3 = b3;
        #pragma unroll
        for (int r = 0; r < RR; ++r) {
            const float rv = rp[r];
            w1 = fmaf(rv, c1[r], w1);
            w2 = fmaf(rv, c2[r], w2);
            w3 = fmaf(rv, c3[r], w3);
        }

        const float evx = ev[eu * 3 + 0];
        const float evy = ev[eu * 3 + 1];
        const float evz = ev[eu * 3 + 2];

        const unsigned int* pp = pk + (size_t)src * 192;
        const unsigned int u1 = pp[lane], u2 = pp[64 + lane], u3 = pp[128 + lane];
        const float f1 = __uint_as_float(u1 & 0xFFFF0000u);
        const float f2 = __uint_as_float(u2 & 0xFFFF0000u);
        const float f3 = __uint_as_float(u3 & 0xFFFF0000u);
        const float v1 = __uint_as_float(u1 << 16);
        const float v2 = __uint_as_float(u2 << 16);
        const float v3 = __uint_as_float(u3 << 16);

        const float cc1 = f1 * w1 * INV_SQRT_3;
        const float cc2 = f2 * w2 * INV_SQRT_3;
        const float cc3 = f3 * w3 * INV_SQRT_3;

        unsafeAtomicAdd(&out_s[(size_t)tgt * 64 + lane], cc3);
        unsafeAtomicAdd(&out_v[(size_t)tgt * 192 + lane],
                        (cc1 * v1 + cc2 * evx) * INV_SQRT_H);
        unsafeAtomicAdd(&out_v[(size_t)tgt * 192 + 64 + lane],
                        (cc1 * v2 + cc2 * evy) * INV_SQRT_H);
        unsafeAtomicAdd(&out_v[(size_t)tgt * 192 + 128 + lane],
                        (cc1 * v3 + cc2 * evz) * INV_SQRT_H);
    }
}

extern "C" void kernel_launch(void* const* d_in, const int* in_sizes, int n_in,
                              void* d_out, int out_size, void* d_ws, size_t ws_size,
                              hipStream_t stream) {
    const float* nf  = (const float*)d_in[0];
    const float* vf  = (const float*)d_in[1];
    const int*   ei  = (const int*)  d_in[2];
    const float* rad = (const float*)d_in[3];
    const float* ev  = (const float*)d_in[4];
    const float* Wf1 = (const float*)d_in[5];
    const float* bf1 = (const float*)d_in[6];
    const float* Wf2 = (const float*)d_in[7];
    const float* bf2 = (const float*)d_in[8];
    const float* Wr  = (const float*)d_in[9];
    const float* br  = (const float*)d_in[10];

    const int N = in_sizes[0] / HH;
    const int E = in_sizes[2] / 2;
    const int nb = (N + SB - 1) / SB;

    float* out_s = (float*)d_out;                // [N,64]
    float* out_v = out_s + (size_t)N * HH;       // [N,3,64]

    // ws layout
    char* ws = (char*)d_ws;
    size_t off = 0;
    unsigned int* pkt = (unsigned int*)(ws + off); off += (size_t)N * 192 * 4;
    int* cnt  = (int*)(ws + off);     off += (size_t)N * 4;
    int* ptr  = (int*)(ws + off);     off += (size_t)(N + 1) * 4;
    int* head = (int*)(ws + off);     off += (size_t)N * 4;
    int* bsum = (int*)(ws + off);     off += (size_t)nb * 4;
    off = (off + 15) & ~(size_t)15;
    int4* meta = (int4*)(ws + off);   off += (size_t)E * 16;

    const int fgrid = min(1280, (N + 7) / 8) > 0 ? min(1280, (N + 7) / 8) : 1;

    if (off <= ws_size) {
        // cnt must be zero before feat2's fused histogram
        hipMemsetAsync(cnt, 0, (size_t)N * 4, stream);
        feat2_kernel<<<fgrid, 256, 0, stream>>>(nf, vf, ei, Wf1, bf1, Wf2, bf2,
                                                pkt, cnt, N, E);
        // outputs accumulated via atomic flushes -> zero first
        hipMemsetAsync(d_out, 0, (size_t)out_size * sizeof(float), stream);

        scanA_kernel<<<nb, SB, 0, stream>>>(cnt, ptr, bsum, N);
        scanB_kernel<<<1, SB, 0, stream>>>(bsum, nb, ptr, N, E);
        scanC_kernel<<<nb, SB, 0, stream>>>(ptr, head, bsum, N);
        fill4_kernel<<<2048, 256, 0, stream>>>(ei, head, meta, E);

        agg11_kernel<<<2048, 256, 0, stream>>>(pkt, rad, ev, Wr, br,
                                               meta, out_s, out_v, E);
    } else {
        hipMemsetAsync(cnt, 0, (size_t)N * 4, stream);
        feat2_kernel<<<fgrid, 256, 0, stream>>>(nf, vf, ei, Wf1, bf1, Wf2, bf2,
                                                pkt, cnt, N, E);
        hipMemsetAsync(d_out, 0, (size_t)out_size * sizeof(float), stream);
        edge_kernel_atomic<<<2048, 256, 0, stream>>>(pkt, ei, rad, ev, Wr, br,
                                                     out_s, out_v, E);
    }
}

// Round 17
// 309.265 us; speedup vs baseline: 1.4297x; 1.0357x over previous
//
#include <hip/hip_runtime.h>
#include <hip/hip_bf16.h>

#define HH 64
#define RR 32
#define SILU_SCALE (1.0f / 0.6f)
#define INV_SQRT_3 0.57735026918962576f
#define INV_SQRT_H 0.125f   // 1/sqrt(64)
#define SB 256              // scan block size

typedef __attribute__((ext_vector_type(8))) short short8;
typedef __attribute__((ext_vector_type(4))) float f32x4;
typedef __attribute__((ext_vector_type(4))) int   i32x4;

__device__ __forceinline__ int rdlane_i(int v, int l) {
    return __builtin_amdgcn_readlane(v, l);
}
__device__ __forceinline__ float rdlane_f(float v, int l) {
    return __uint_as_float(__builtin_amdgcn_readlane(__float_as_uint(v), l));
}
__device__ __forceinline__ ushort bf16u(float x) {
    __hip_bfloat16 h = __float2bfloat16(x);
    return *(ushort*)&h;
}
__device__ __forceinline__ float bf16f(ushort u) {
    return __uint_as_float((unsigned int)u << 16);
}

// ---------------------------------------------------------------------------
// Kernel 1: feat_w -> packed table pk[n][c] = (bf16(fw)<<16)|bf16(vf).
// Fused target histogram (cnt pre-zeroed by host memset). (Verified r13/r16.)
// ---------------------------------------------------------------------------
__global__ __launch_bounds__(256) void feat2_kernel(
    const float* __restrict__ nf,
    const float* __restrict__ vf,
    const int*   __restrict__ ei,
    const float* __restrict__ Wf1, const float* __restrict__ bf1,
    const float* __restrict__ Wf2, const float* __restrict__ bf2,
    unsigned int* __restrict__ pk, int* __restrict__ cnt, int N, int E)
{
    __shared__ float sW1[64 * 32];
    __shared__ float sW2[32 * 192];
    __shared__ float sb1[32];
    __shared__ float sb2[192];
    __shared__ float snf[8 * 66];   // 64 + 2 pad
    __shared__ float sh[8 * 34];    // 32 + 2 pad

    const int tid = threadIdx.x;
    // histogram (cnt zeroed by memset before this kernel)
    for (int e = blockIdx.x * 256 + tid; e < E; e += gridDim.x * 256)
        atomicAdd(&cnt[ei[E + e]], 1);

    for (int i = tid; i < 64 * 32; i += 256) sW1[i] = Wf1[i];
    for (int i = tid; i < 32 * 192; i += 256) sW2[i] = Wf2[i];
    if (tid < 32) sb1[tid] = bf1[tid];
    if (tid < 192) sb2[tid] = bf2[tid];
    __syncthreads();

    const int sub = tid >> 5;
    const int l32 = tid & 31;

    for (int n0 = blockIdx.x * 8; n0 < N; n0 += gridDim.x * 8) {
        const int nrem = min(8, N - n0);
        for (int i = tid; i < nrem * 64; i += 256)
            snf[(i >> 6) * 66 + (i & 63)] = nf[(size_t)n0 * 64 + i];
        __syncthreads();

        const int n = n0 + sub;
        {
            float a = sb1[l32];
            const float* x = &snf[sub * 66];
            #pragma unroll
            for (int i = 0; i < 64; ++i)
                a = fmaf(x[i], sW1[i * 32 + l32], a);
            sh[sub * 34 + l32] = a / (1.0f + __expf(-a)) * SILU_SCALE;
        }
        // sh written/read within the same 32-lane group -> no barrier
        if (n < N) {
            #pragma unroll
            for (int k = 0; k < 6; ++k) {
                const int col = l32 + 32 * k;
                const float vvf = vf[(size_t)n * 192 + col];
                float o = sb2[col];
                #pragma unroll
                for (int j = 0; j < 32; ++j)
                    o = fmaf(sh[sub * 34 + j], sW2[j * 192 + col], o);
                pk[(size_t)n * 192 + col] =
                    ((unsigned int)bf16u(o) << 16) | (unsigned int)bf16u(vvf);
            }
        }
        __syncthreads();
    }
}

// ---------------------------------------------------------------------------
// Counting sort by target: scan -> fill (int4 meta: 16B/edge random)
// ---------------------------------------------------------------------------
__global__ __launch_bounds__(SB) void scanA_kernel(
    const int* __restrict__ cnt, int* __restrict__ ptr,
    int* __restrict__ bsum, int N)
{
    __shared__ int s[SB];
    const int t = threadIdx.x;
    const int i = blockIdx.x * SB + t;
    const int v = (i < N) ? cnt[i] : 0;
    s[t] = v; __syncthreads();
    for (int off = 1; off < SB; off <<= 1) {
        int x = (t >= off) ? s[t - off] : 0;
        __syncthreads();
        s[t] += x;
        __syncthreads();
    }
    if (i < N) ptr[i] = s[t] - v;
    if (t == SB - 1) bsum[blockIdx.x] = s[t];
}

__global__ __launch_bounds__(SB) void scanB_kernel(
    int* __restrict__ bsum, int nb, int* __restrict__ ptr, int N, int E)
{
    __shared__ int s[SB];
    const int t = threadIdx.x;
    int carry = 0;
    for (int base = 0; base < nb; base += SB) {
        const int i = base + t;
        const int v = (i < nb) ? bsum[i] : 0;
        s[t] = v; __syncthreads();
        for (int off = 1; off < SB; off <<= 1) {
            int x = (t >= off) ? s[t - off] : 0;
            __syncthreads();
            s[t] += x;
            __syncthreads();
        }
        const int total = s[SB - 1];
        if (i < nb) bsum[i] = carry + s[t] - v;
        carry += total;
        __syncthreads();
    }
    if (t == 0) ptr[N] = E;
}

__global__ __launch_bounds__(SB) void scanC_kernel(
    int* __restrict__ ptr, int* __restrict__ head,
    const int* __restrict__ bsum, int N)
{
    const int i = blockIdx.x * SB + threadIdx.x;
    if (i < N) {
        const int p = ptr[i] + bsum[blockIdx.x];
        ptr[i] = p;
        head[i] = p;
    }
}

__global__ __launch_bounds__(256) void fill4_kernel(
    const int* __restrict__ ei, int* __restrict__ head,
    int4* __restrict__ meta, int E)
{
    for (int e = blockIdx.x * blockDim.x + threadIdx.x; e < E;
         e += gridDim.x * blockDim.x) {
        const int t = ei[E + e];
        const int pos = atomicAdd(&head[t], 1);
        meta[pos] = make_int4(e, ei[e], t, 0);
    }
}

// ---------------------------------------------------------------------------
// agg14 = agg11 (r16-verified, 159us) with ONE cache-policy change:
// the streaming operands (meta row, rad row) use NON-TEMPORAL loads so the
// 115MB of read-once data stops evicting the 38MB pk gather table from
// L2/L3 (~190MB of pk re-fetches in r16's FETCH=408MB). Dataflow, register
// pressure, and all arithmetic are unchanged. A/B vs r16; revert if
// VGPR_Count != 64 or FETCH rises.
// ---------------------------------------------------------------------------
__global__ __launch_bounds__(256, 4) void agg14_kernel(
    const unsigned int* __restrict__ pk,   // [N,192] packed bf16 (fw|vf)
    const float* __restrict__ rad,         // [E,32] f32, edge order
    const float* __restrict__ ev,          // [E,3]  edge order
    const float* __restrict__ Wr,          // [32,192]
    const float* __restrict__ br,          // [192]
    const int4* __restrict__ meta,         // [E] (edge,src,tgt,0) CSR-sorted
    float* __restrict__ out_s,             // [N,64]
    float* __restrict__ out_v,             // [N,3,64]
    int E)
{
    __shared__ __align__(16) ushort sBf[12 * 64 * 8];    // 12KB Wr B-frags
    __shared__ __align__(16) ushort Pl[4][16 * 200];     // 25.6KB P slices

    const int tid  = threadIdx.x;
    const int lane = tid & 63;
    const int w    = tid >> 6;
    const int mr   = lane & 15;
    const int kk   = (lane >> 4) * 8;       // k offset in bf16 elems

    // stage B fragments (r11/r16-verified layout, unscaled)
    for (int i = tid; i < 12 * 64 * 8; i += 256) {
        const int nt = i >> 9;
        const int l  = (i >> 3) & 63;
        const int j  = i & 7;
        sBf[i] = bf16u(Wr[(((l >> 4) & 3) * 8 + j) * 192 + nt * 16 + (l & 15)]);
    }
    __syncthreads();

    const float b1 = br[lane], b2 = br[64 + lane], b3 = br[128 + lane];
    ushort* Pw = Pl[w];
    const int gwave  = blockIdx.x * 4 + w;
    const int nwaves = gridDim.x * 4;
    const int nchunk = (E + 15) >> 4;

    for (int c = gwave; c < nchunk; c += nwaves) {
        const int base = c << 4;
        const int m = min(16, E - base);
        const int idx = min(base + mr, E - 1);

        // slot mr's (edge, src, tgt) — NON-TEMPORAL (streaming, read-once)
        const i32x4 mtv = __builtin_nontemporal_load((const i32x4*)(meta + idx));
        const int mtx = mtv[0];
        const int mty = mtv[1];
        const int mtz = mtv[2];

        // A fragment source: f32 rad row — NON-TEMPORAL (streaming)
        const float* rp = rad + (size_t)mtx * RR + kk;
        const f32x4 ra = __builtin_nontemporal_load((const f32x4*)rp);
        const f32x4 rb = __builtin_nontemporal_load((const f32x4*)(rp + 4));

        // ---- wave-parallel ev hoist: lane l holds comp l%3 of slot l/3 ----
        const int sl  = lane / 3;                    // 0..21
        const int sle = min(sl, m - 1);              // clamp (<16)
        const int esl = __shfl(mtx, sle);            // edge id at that slot
        const float evv = ev[3 * (size_t)esl + (lane - 3 * sl)];

        // ---- hoisted pk gathers: all 16 slots, statically indexed (r16) ----
        unsigned int u0[16], u1[16], u2[16];
        #pragma unroll
        for (int i = 0; i < 16; ++i) {
            const int sc = rdlane_i(mty, min(i, m - 1));   // SGPR idx
            const unsigned int* pp = pk + (size_t)sc * 192;
            u0[i] = pp[lane];
            u1[i] = pp[64 + lane];
            u2[i] = pp[128 + lane];
        }

        short8 a0;
        a0[0] = (short)bf16u(ra[0]); a0[1] = (short)bf16u(ra[1]);
        a0[2] = (short)bf16u(ra[2]); a0[3] = (short)bf16u(ra[3]);
        a0[4] = (short)bf16u(rb[0]); a0[5] = (short)bf16u(rb[1]);
        a0[6] = (short)bf16u(rb[2]); a0[7] = (short)bf16u(rb[3]);

        // MFMA: P[16][192] = A[16][32] @ Wr[32][192] -> bf16 LDS (swizzled)
        #pragma unroll
        for (int nt = 0; nt < 12; ++nt) {
            const short8 b = *(const short8*)&sBf[(nt * 64 + lane) * 8];
            f32x4 c0 = {0.f, 0.f, 0.f, 0.f};
            c0 = __builtin_amdgcn_mfma_f32_16x16x32_bf16(a0, b, c0, 0, 0, 0);
            #pragma unroll
            for (int r = 0; r < 4; ++r) {
                const int row = ((lane >> 4) << 2) + r;   // C: row=(lane>>4)*4+reg
                *(ushort*)((char*)Pw + row * 400 +
                           ((nt * 32 + mr * 2) ^ ((row & 12) << 3))) = bf16u(c0[r]);
            }
        }

        // run-boundary flags (r5/r16-verified)
        const int tg = mtz;
        const int tnext = __shfl(tg, min(mr + 1, 15));
        const int bnd = (mr == m - 1) || (tnext != tg);

        // --- math loop: r16-verified unrolled sweep; ev via readlane ---
        float as = 0.f, ax = 0.f, ay = 0.f, az = 0.f;
        #pragma unroll
        for (int i = 0; i < 16; ++i) {
            if (i >= m) break;               // wave-uniform
            const int t  = rdlane_i(mtz, i);
            const int fl = rdlane_i(bnd, i);
            const float ex = rdlane_f(evv, 3 * i + 0);
            const float ey = rdlane_f(evv, 3 * i + 1);
            const float ez = rdlane_f(evv, 3 * i + 2);

            const int swz = (i & 12) << 3;
            const char* prow = (const char*)Pw + i * 400;
            ushort q1 = *(const ushort*)(prow + ((lane * 2) ^ swz));
            ushort q2 = *(const ushort*)(prow + (((64 + lane) * 2) ^ swz));
            ushort q3 = *(const ushort*)(prow + (((128 + lane) * 2) ^ swz));
            const float p1 = bf16f(q1) + b1;
            const float p2 = bf16f(q2) + b2;
            const float p3 = bf16f(q3) + b3;

            const float f1 = __uint_as_float(u0[i] & 0xFFFF0000u);
            const float f2 = __uint_as_float(u1[i] & 0xFFFF0000u);
            const float f3 = __uint_as_float(u2[i] & 0xFFFF0000u);
            const float v1 = __uint_as_float(u0[i] << 16);
            const float v2 = __uint_as_float(u1[i] << 16);
            const float v3 = __uint_as_float(u2[i] << 16);

            const float cc1 = f1 * p1 * INV_SQRT_3;
            const float cc2 = f2 * p2 * INV_SQRT_3;
            const float cc3 = f3 * p3 * INV_SQRT_3;

            as += cc3;
            ax = fmaf(cc1, v1, fmaf(cc2, ex, ax));
            ay = fmaf(cc1, v2, fmaf(cc2, ey, ay));
            az = fmaf(cc1, v3, fmaf(cc2, ez, az));

            if (fl) {   // wave-uniform flush at target-run boundary
                unsafeAtomicAdd(&out_s[(size_t)t * 64 + lane], as);
                unsafeAtomicAdd(&out_v[(size_t)t * 192 + lane],       ax * INV_SQRT_H);
                unsafeAtomicAdd(&out_v[(size_t)t * 192 + 64 + lane],  ay * INV_SQRT_H);
                unsafeAtomicAdd(&out_v[(size_t)t * 192 + 128 + lane], az * INV_SQRT_H);
                as = ax = ay = az = 0.f;
            }
        }
    }
}

// ---------------------------------------------------------------------------
// Fallback (atomic scatter) if ws can't hold scratch; uses packed table.
// ---------------------------------------------------------------------------
__global__ __launch_bounds__(256) void edge_kernel_atomic(
    const unsigned int* __restrict__ pk, const int* __restrict__ ei,
    const float* __restrict__ rad, const float* __restrict__ ev,
    const float* __restrict__ Wr, const float* __restrict__ br,
    float* __restrict__ out_s, float* __restrict__ out_v, int E)
{
    const int lane = threadIdx.x & 63;
    const int wid  = __builtin_amdgcn_readfirstlane((int)(threadIdx.x >> 6));
    const int wavesPerBlock = blockDim.x >> 6;
    const int totalWaves = gridDim.x * wavesPerBlock;
    const int w0 = blockIdx.x * wavesPerBlock + wid;

    float c1[RR], c2[RR], c3[RR];
    #pragma unroll
    for (int r = 0; r < RR; ++r) {
        c1[r] = Wr[r * 192 + lane];
        c2[r] = Wr[r * 192 + 64 + lane];
        c3[r] = Wr[r * 192 + 128 + lane];
    }
    const float b1 = br[lane], b2 = br[64 + lane], b3 = br[128 + lane];

    for (int e = w0; e < E; e += totalWaves) {
        const int eu  = __builtin_amdgcn_readfirstlane(e);
        const int src = ei[eu];
        const int tgt = ei[E + eu];

        const float* rp = rad + (size_t)eu * RR;
        float w1 = b1, w2 = b2, w3 = b3;
        #pragma unroll
        for (int r = 0; r < RR; ++r) {
            const float rv = rp[r];
            w1 = fmaf(rv, c1[r], w1);
            w2 = fmaf(rv, c2[r], w2);
            w3 = fmaf(rv, c3[r], w3);
        }

        const float evx = ev[eu * 3 + 0];
        const float evy = ev[eu * 3 + 1];
        const float evz = ev[eu * 3 + 2];

        const unsigned int* pp = pk + (size_t)src * 192;
        const unsigned int u1 = pp[lane], u2 = pp[64 + lane], u3 = pp[128 + lane];
        const float f1 = __uint_as_float(u1 & 0xFFFF0000u);
        const float f2 = __uint_as_float(u2 & 0xFFFF0000u);
        const float f3 = __uint_as_float(u3 & 0xFFFF0000u);
        const float v1 = __uint_as_float(u1 << 16);
        const float v2 = __uint_as_float(u2 << 16);
        const float v3 = __uint_as_float(u3 << 16);

        const float cc1 = f1 * w1 * INV_SQRT_3;
        const float cc2 = f2 * w2 * INV_SQRT_3;
        const float cc3 = f3 * w3 * INV_SQRT_3;

        unsafeAtomicAdd(&out_s[(size_t)tgt * 64 + lane], cc3);
        unsafeAtomicAdd(&out_v[(size_t)tgt * 192 + lane],
                        (cc1 * v1 + cc2 * evx) * INV_SQRT_H);
        unsafeAtomicAdd(&out_v[(size_t)tgt * 192 + 64 + lane],
                        (cc1 * v2 + cc2 * evy) * INV_SQRT_H);
        unsafeAtomicAdd(&out_v[(size_t)tgt * 192 + 128 + lane],
                        (cc1 * v3 + cc2 * evz) * INV_SQRT_H);
    }
}

extern "C" void kernel_launch(void* const* d_in, const int* in_sizes, int n_in,
                              void* d_out, int out_size, void* d_ws, size_t ws_size,
                              hipStream_t stream) {
    const float* nf  = (const float*)d_in[0];
    const float* vf  = (const float*)d_in[1];
    const int*   ei  = (const int*)  d_in[2];
    const float* rad = (const float*)d_in[3];
    const float* ev  = (const float*)d_in[4];
    const float* Wf1 = (const float*)d_in[5];
    const float* bf1 = (const float*)d_in[6];
    const float* Wf2 = (const float*)d_in[7];
    const float* bf2 = (const float*)d_in[8];
    const float* Wr  = (const float*)d_in[9];
    const float* br  = (const float*)d_in[10];

    const int N = in_sizes[0] / HH;
    const int E = in_sizes[2] / 2;
    const int nb = (N + SB - 1) / SB;

    float* out_s = (float*)d_out;                // [N,64]
    float* out_v = out_s + (size_t)N * HH;       // [N,3,64]

    // ws layout
    char* ws = (char*)d_ws;
    size_t off = 0;
    unsigned int* pkt = (unsigned int*)(ws + off); off += (size_t)N * 192 * 4;
    int* cnt  = (int*)(ws + off);     off += (size_t)N * 4;
    int* ptr  = (int*)(ws + off);     off += (size_t)(N + 1) * 4;
    int* head = (int*)(ws + off);     off += (size_t)N * 4;
    int* bsum = (int*)(ws + off);     off += (size_t)nb * 4;
    off = (off + 15) & ~(size_t)15;
    int4* meta = (int4*)(ws + off);   off += (size_t)E * 16;

    const int fgrid = min(1280, (N + 7) / 8) > 0 ? min(1280, (N + 7) / 8) : 1;

    if (off <= ws_size) {
        // cnt must be zero before feat2's fused histogram
        hipMemsetAsync(cnt, 0, (size_t)N * 4, stream);
        feat2_kernel<<<fgrid, 256, 0, stream>>>(nf, vf, ei, Wf1, bf1, Wf2, bf2,
                                                pkt, cnt, N, E);
        // outputs accumulated via atomic flushes -> zero first
        hipMemsetAsync(d_out, 0, (size_t)out_size * sizeof(float), stream);

        scanA_kernel<<<nb, SB, 0, stream>>>(cnt, ptr, bsum, N);
        scanB_kernel<<<1, SB, 0, stream>>>(bsum, nb, ptr, N, E);
        scanC_kernel<<<nb, SB, 0, stream>>>(ptr, head, bsum, N);
        fill4_kernel<<<4096, 256, 0, stream>>>(ei, head, meta, E);

        agg14_kernel<<<2048, 256, 0, stream>>>(pkt, rad, ev, Wr, br,
                                               meta, out_s, out_v, E);
    } else {
        hipMemsetAsync(cnt, 0, (size_t)N * 4, stream);
        feat2_kernel<<<fgrid, 256, 0, stream>>>(nf, vf, ei, Wf1, bf1, Wf2, bf2,
                                                pkt, cnt, N, E);
        hipMemsetAsync(d_out, 0, (size_t)out_size * sizeof(float), stream);
        edge_kernel_atomic<<<2048, 256, 0, stream>>>(pkt, ei, rad, ev, Wr, br,
                                                     out_s, out_v, E);
    }
}